// Round 4
// baseline (1618.334 us; speedup 1.0000x reference)
//
#include <hip/hip_runtime.h>
#include <hip/hip_bf16.h>

// Problem constants (fixed by setup_inputs)
#define BB 4
#define HH 12
#define PP 1568
#define TT 8
#define DD 196          // PP / FRAME_T
#define HD 64
#define NUMK 10
#define NBH (BB*HH)     // 48
#define NBLK (NBH*PP)   // 75264
#define NRED1 (NBLK/256) // 294
#define VROW (TT*HD)    // 512 floats between consecutive d-rows of v
#define NEG_INF (-3.0e38f)

typedef unsigned long long ull;

__device__ __forceinline__ float readlane_f(float v, int l) {
    return __int_as_float(__builtin_amdgcn_readlane(__float_as_int(v), l));
}

// wave-wide sum, uniform result.
__device__ __forceinline__ float wave_sum_u(float v) {
#define STEPS(ctrl) { float t_ = __int_as_float(__builtin_amdgcn_update_dpp( \
        0, __float_as_int(v), ctrl, 0xF, 0xF, true)); v += t_; }
    STEPS(0x111) STEPS(0x112) STEPS(0x114) STEPS(0x118) STEPS(0x142) STEPS(0x143)
#undef STEPS
    return readlane_f(v, 63);
}

// Monotone u32 -> float order-preserving transform inverse.
__device__ __forceinline__ float untrans(unsigned v) {
    unsigned u = (v & 0x80000000u) ? (v ^ 0x80000000u) : ~v;
    return __uint_as_float(u);
}

#define T_LO 0x3E0FFFFFu   // t(-30.0f)
#define T_HI 0xC1F00000u   // t(+30.0f)
#define T_P0 0xC0400000u   // t(3.0f)  scripted probe 0
#define T_P1 0xBF800000u   // t(1.0f)  scripted probe 1

// Bisection state for one row (wave-uniform -> SGPRs).
struct BiState {
    unsigned lo, hi, tau;
    bool done, needEpi;
    ull m0, m1, m2, m3;
};

__device__ __forceinline__ void bi_step(BiState& st, const float4& a, int it) {
    if (st.done) return;
    unsigned mid;
    if (it == 0)      mid = T_P0;
    else if (it == 1) mid = T_P1;
    else              mid = st.lo + ((st.hi - st.lo) >> 1);
    unsigned lo1 = st.lo + 1, hi1 = st.hi - 1;
    mid = (mid < lo1) ? lo1 : (mid > hi1) ? hi1 : mid;
    float tf = untrans(mid);
    ull c0 = __ballot(a.x >= tf);
    ull c1 = __ballot(a.y >= tf);
    ull c2 = __ballot(a.z >= tf);
    ull c3 = __ballot(a.w >= tf);
    int cnt = __popcll(c0) + __popcll(c1) + __popcll(c2) + __popcll(c3);
    cnt = __builtin_amdgcn_readfirstlane(cnt);
    if (cnt == NUMK) {
        st.tau = mid; st.done = true; st.needEpi = false;
        st.m0 = c0; st.m1 = c1; st.m2 = c2; st.m3 = c3;
    } else {
        if (cnt > NUMK) st.lo = mid; else st.hi = mid;
        if (st.hi - st.lo <= 1) {      // collapse: fp32 tie at the margin
            st.tau = st.lo; st.done = true; st.needEpi = true;
        }
    }
}

__device__ __forceinline__ void bi_finish(BiState& st, const float4& a) {
    if (st.needEpi) {   // recompute kept masks at final tau (rare path)
        float tf = untrans(st.tau);
        st.m0 = __ballot(a.x >= tf);
        st.m1 = __ballot(a.y >= tf);
        st.m2 = __ballot(a.z >= tf);
        st.m3 = __ballot(a.w >= tf);
    }
}

__device__ __forceinline__ float4 make_w(const BiState& st, const float4& a) {
    float tf = untrans(st.tau);
    float4 w;
    w.x = __expf(a.x - tf);
    w.y = __expf(a.y - tf);
    w.z = __expf(a.z - tf);
    w.w = __expf(a.w - tf);
    return w;
}

// Extract NUMK kept (index, weight) pairs from the masks (masks modified).
// Fully unrolled -> all arrays static-indexed -> registers. kept count is
// always >= NUMK (bracket invariant: cnt(lo)=196 > 10 initially).
__device__ __forceinline__ void extract10(ull& e0, ull& e1, ull& e2, ull& e3,
        const float4& w, int* didx, float* wk) {
#pragma unroll
    for (int k = 0; k < NUMK; ++k) {
        ull p0 = e0, p1 = e1, p2 = e2, p3 = e3;
        ull pick = p0 ? p0 : (p1 ? p1 : (p2 ? p2 : p3));
        int j    = p0 ? 0  : (p1 ? 1  : (p2 ? 2  : 3));
        int l    = (int)__ffsll(pick) - 1;
        ull low  = pick & (~pick + 1ull);
        e0 = (j == 0) ? (e0 ^ low) : e0;
        e1 = (j == 1) ? (e1 ^ low) : e1;
        e2 = (j == 2) ? (e2 ^ low) : e2;
        e3 = (j == 3) ? (e3 ^ low) : e3;
        float wsel = (j == 0) ? w.x : (j == 1) ? w.y : (j == 2) ? w.z : w.w;
        didx[k] = 4 * l + j;          // lane l holds elements 4l..4l+3
        wk[k]   = readlane_f(wsel, l);
    }
}

// Rare tail: kept elements beyond the first NUMK (exact fp32 ties).
__device__ __noinline__ void gather_tail(ull e0, ull e1, ull e2, ull e3,
        const float4& w, const float* __restrict__ vbt, int lane,
        float& o, float& wsum) {
#pragma unroll
    for (int j = 0; j < 4; ++j) {
        ull   mm = (j==0)?e0:(j==1)?e1:(j==2)?e2:e3;
        float ws = (j==0)?w.x:(j==1)?w.y:(j==2)?w.z:w.w;
        while (mm) {
            int l = (int)__ffsll(mm) - 1; mm &= mm - 1;
            float wa = readlane_f(ws, l);
            o = fmaf(wa, vbt[(size_t)(4*l + j)*VROW + lane], o);
            wsum += wa;
        }
    }
}

// Process the s-row and t-row for one (bh,p,t): joint bisection (scalar-pipe
// bracket updates), then batched gather: all 20 loads issued back-to-back,
// single drain, accumulate.
__device__ __forceinline__ void process_pair(
        const float4& a, const float4& b,
        const float* __restrict__ vbtS, const float* __restrict__ vbtT,
        int lane, float& osR, float& otR)
{
    BiState S, T;
    S.lo = T_LO; S.hi = T_HI; S.done = false; S.needEpi = true; S.tau = T_LO;
    T.lo = T_LO; T.hi = T_HI; T.done = false; T.needEpi = true; T.tau = T_LO;

    for (int it = 0; it < 40 && !(S.done && T.done); ++it) {
        bi_step(S, a, it);
        bi_step(T, b, it);
    }
    bi_finish(S, a);
    bi_finish(T, b);

    float4 wS = make_w(S, a);
    float4 wT = make_w(T, b);

    ull s0 = S.m0, s1 = S.m1, s2 = S.m2, s3 = S.m3;
    ull t0 = T.m0, t1 = T.m1, t2 = T.m2, t3 = T.m3;
    int   dS[NUMK], dT[NUMK];
    float fS[NUMK], fT[NUMK];
    extract10(s0, s1, s2, s3, wS, dS, fS);
    extract10(t0, t1, t2, t3, wT, dT, fT);

    // issue all 20 loads; compiler clusters them, one vmcnt drain at first use
    float gS[NUMK], gT[NUMK];
#pragma unroll
    for (int k = 0; k < NUMK; ++k) gS[k] = vbtS[(size_t)dS[k] * VROW + lane];
#pragma unroll
    for (int k = 0; k < NUMK; ++k) gT[k] = vbtT[(size_t)dT[k] * VROW + lane];

    float oS = 0.f, wsS = 0.f, oT = 0.f, wsT = 0.f;
#pragma unroll
    for (int k = 0; k < NUMK; ++k) { oS = fmaf(fS[k], gS[k], oS); wsS += fS[k]; }
#pragma unroll
    for (int k = 0; k < NUMK; ++k) { oT = fmaf(fT[k], gT[k], oT); wsT += fT[k]; }

    if (__builtin_expect((s0 | s1 | s2 | s3) != 0ull, 0))
        gather_tail(s0, s1, s2, s3, wS, vbtS, lane, oS, wsS);
    if (__builtin_expect((t0 | t1 | t2 | t3) != 0ull, 0))
        gather_tail(t0, t1, t2, t3, wT, vbtT, lane, oT, wsT);

    osR = oS * __builtin_amdgcn_rcpf(wsS);
    otR = oT * __builtin_amdgcn_rcpf(wsT);
}

__global__ __launch_bounds__(256, 8) void vtop_main(
        const float* __restrict__ att_s, const float* __restrict__ att_t,
        const float* __restrict__ v_s,   const float* __restrict__ v_t,
        float* __restrict__ partial) {
    int bid  = blockIdx.x;
    int p    = bid % PP;
    int bh   = bid / PP;
    int lane = threadIdx.x & 63;
    int wid  = threadIdx.x >> 6;

    size_t rowbase = ((size_t)bh * PP + p) * PP;
    const float* rs = att_s + rowbase;
    const float* rt = att_t + rowbase;
    size_t vbase = (size_t)bh * PP * HD;
    int t0 = wid * 2, t1 = t0 + 1;

    // hoist all 4 att-row loads: one HBM round trip for the whole wave
    float4 a0, b0, a1, b1;
    if (lane < 49) {            // 196 = 49*4; 16B-aligned (784 = 49*16)
        a0 = *(const float4*)(rs + t0 * DD + 4 * lane);
        b0 = *(const float4*)(rt + t0 * DD + 4 * lane);
        a1 = *(const float4*)(rs + t1 * DD + 4 * lane);
        b1 = *(const float4*)(rt + t1 * DD + 4 * lane);
    } else {
        float4 ninf; ninf.x = ninf.y = ninf.z = ninf.w = NEG_INF;
        a0 = b0 = a1 = b1 = ninf;
    }

    float acc = 0.f, os, ot;
    process_pair(a0, b0, v_s + vbase + t0 * HD, v_t + vbase + t0 * HD, lane, os, ot);
    { float d = os - ot; acc = fmaf(d, d, acc); }
    process_pair(a1, b1, v_s + vbase + t1 * HD, v_t + vbase + t1 * HD, lane, os, ot);
    { float d = os - ot; acc = fmaf(d, d, acc); }

    float wtot = wave_sum_u(acc);
    __shared__ float sm[4];
    if (lane == 0) sm[wid] = wtot;
    __syncthreads();
    if (threadIdx.x == 0) {
        partial[bid] = sm[0] + sm[1] + sm[2] + sm[3];
    }
}

// stage 1: 294 blocks x 256 -> 294 partials (parallel, latency-friendly)
__global__ __launch_bounds__(256) void vtop_reduce1(
        const float* __restrict__ partial, float* __restrict__ p2) {
    int i = blockIdx.x * 256 + threadIdx.x;
    float wtot = wave_sum_u(partial[i]);
    __shared__ float sm[4];
    int lane = threadIdx.x & 63, wid = threadIdx.x >> 6;
    if (lane == 0) sm[wid] = wtot;
    __syncthreads();
    if (threadIdx.x == 0) p2[blockIdx.x] = sm[0] + sm[1] + sm[2] + sm[3];
}

// stage 2: single block over 294 values
__global__ __launch_bounds__(256) void vtop_reduce2(
        const float* __restrict__ p2, float* __restrict__ out) {
    __shared__ double smd[256];
    double a = 0.0;
    for (int i = threadIdx.x; i < NRED1; i += 256) a += (double)p2[i];
    smd[threadIdx.x] = a;
    __syncthreads();
    for (int s = 128; s > 0; s >>= 1) {
        if (threadIdx.x < s) smd[threadIdx.x] += smd[threadIdx.x + s];
        __syncthreads();
    }
    if (threadIdx.x == 0) {
        const double inv_n = 1.0 / ((double)NBH * PP * TT * HD);  // 1/38535168
        out[0] = (float)(smd[0] * inv_n);
    }
}

extern "C" void kernel_launch(void* const* d_in, const int* in_sizes, int n_in,
                              void* d_out, int out_size, void* d_ws, size_t ws_size,
                              hipStream_t stream) {
    const float* att_s = (const float*)d_in[0];
    const float* att_t = (const float*)d_in[1];
    const float* v_s   = (const float*)d_in[2];
    const float* v_t   = (const float*)d_in[3];
    float* out     = (float*)d_out;
    float* partial = (float*)d_ws;                 // NBLK floats
    float* p2      = (float*)d_ws + NBLK;          // NRED1 floats

    vtop_main<<<NBLK, 256, 0, stream>>>(att_s, att_t, v_s, v_t, partial);
    vtop_reduce1<<<NRED1, 256, 0, stream>>>(partial, p2);
    vtop_reduce2<<<1, 256, 0, stream>>>(p2, out);
}

// Round 5
// 1579.025 us; speedup vs baseline: 1.0249x; 1.0249x over previous
//
#include <hip/hip_runtime.h>
#include <hip/hip_bf16.h>

// Problem constants (fixed by setup_inputs)
#define BB 4
#define HH 12
#define PP 1568
#define TT 8
#define DD 196          // PP / FRAME_T
#define HD 64
#define NUMK 10
#define NBH (BB*HH)     // 48
#define NBLK (NBH*PP)   // 75264
#define NRED1 (NBLK/256) // 294
#define VROW (TT*HD)    // 512 floats between consecutive d-rows of v
#define NEG_INF (-3.0e38f)

typedef unsigned long long ull;

__device__ __forceinline__ float readlane_f(float v, int l) {
    return __int_as_float(__builtin_amdgcn_readlane(__float_as_int(v), l));
}

// wave-wide sum, uniform result.
__device__ __forceinline__ float wave_sum_u(float v) {
#define STEPS(ctrl) { float t_ = __int_as_float(__builtin_amdgcn_update_dpp( \
        0, __float_as_int(v), ctrl, 0xF, 0xF, true)); v += t_; }
    STEPS(0x111) STEPS(0x112) STEPS(0x114) STEPS(0x118) STEPS(0x142) STEPS(0x143)
#undef STEPS
    return readlane_f(v, 63);
}

// Monotone u32 -> float order-preserving transform inverse.
__device__ __forceinline__ float untrans(unsigned v) {
    unsigned u = (v & 0x80000000u) ? (v ^ 0x80000000u) : ~v;
    return __uint_as_float(u);
}

#define T_LO 0x3E0FFFFFu   // t(-30.0f)
#define T_HI 0xC1F00000u   // t(+30.0f)
#define T_P0 0xC0400000u   // t(3.0f)  scripted probe 0
#define T_P1 0xBF800000u   // t(1.0f)  scripted probe 1

// Bisection state for one row (wave-uniform -> SGPRs).
struct BiState {
    unsigned lo, hi, tau;
    bool done, needEpi;
    ull m0, m1, m2, m3;
};

__device__ __forceinline__ void bi_step(BiState& st, const float4& a, int it) {
    if (st.done) return;
    unsigned mid;
    if (it == 0)      mid = T_P0;
    else if (it == 1) mid = T_P1;
    else              mid = st.lo + ((st.hi - st.lo) >> 1);
    unsigned lo1 = st.lo + 1, hi1 = st.hi - 1;
    mid = (mid < lo1) ? lo1 : (mid > hi1) ? hi1 : mid;
    float tf = untrans(mid);
    ull c0 = __ballot(a.x >= tf);
    ull c1 = __ballot(a.y >= tf);
    ull c2 = __ballot(a.z >= tf);
    ull c3 = __ballot(a.w >= tf);
    int cnt = __popcll(c0) + __popcll(c1) + __popcll(c2) + __popcll(c3);
    cnt = __builtin_amdgcn_readfirstlane(cnt);
    if (cnt == NUMK) {
        st.tau = mid; st.done = true; st.needEpi = false;
        st.m0 = c0; st.m1 = c1; st.m2 = c2; st.m3 = c3;
    } else {
        if (cnt > NUMK) st.lo = mid; else st.hi = mid;
        if (st.hi - st.lo <= 1) {      // collapse: fp32 tie at the margin
            st.tau = st.lo; st.done = true; st.needEpi = true;
        }
    }
}

__device__ __forceinline__ void bi_finish(BiState& st, const float4& a) {
    if (st.needEpi) {   // recompute kept masks at final tau (rare path)
        float tf = untrans(st.tau);
        st.m0 = __ballot(a.x >= tf);
        st.m1 = __ballot(a.y >= tf);
        st.m2 = __ballot(a.z >= tf);
        st.m3 = __ballot(a.w >= tf);
    }
}

__device__ __forceinline__ float4 make_w(const BiState& st, const float4& a) {
    float tf = untrans(st.tau);
    float4 w;
    w.x = __expf(a.x - tf);
    w.y = __expf(a.y - tf);
    w.z = __expf(a.z - tf);
    w.w = __expf(a.w - tf);
    return w;
}

// Extract NUMK kept (index, weight) pairs from the masks (masks modified).
// Fully unrolled -> static indexing -> registers; indices & weights are
// wave-uniform (derived from scalar masks + readlane) -> SGPRs.
__device__ __forceinline__ void extract10(ull& e0, ull& e1, ull& e2, ull& e3,
        const float4& w, int* didx, float* wk) {
#pragma unroll
    for (int k = 0; k < NUMK; ++k) {
        ull p0 = e0, p1 = e1, p2 = e2, p3 = e3;
        ull pick = p0 ? p0 : (p1 ? p1 : (p2 ? p2 : p3));
        int j    = p0 ? 0  : (p1 ? 1  : (p2 ? 2  : 3));
        int l    = (int)__ffsll(pick) - 1;
        ull low  = pick & (~pick + 1ull);
        e0 = (j == 0) ? (e0 ^ low) : e0;
        e1 = (j == 1) ? (e1 ^ low) : e1;
        e2 = (j == 2) ? (e2 ^ low) : e2;
        e3 = (j == 3) ? (e3 ^ low) : e3;
        float wsel = (j == 0) ? w.x : (j == 1) ? w.y : (j == 2) ? w.z : w.w;
        didx[k] = 4 * l + j;          // lane l holds elements 4l..4l+3
        wk[k]   = readlane_f(wsel, l);
    }
}

// Rare tail: kept elements beyond the first NUMK (exact fp32 ties).
// MUST be inlined: taking addresses of o/wsum across a call boundary forces
// the hot-path accumulators to scratch (R4: 1.76 GB of scratch writes).
__device__ __forceinline__ void gather_tail(ull e0, ull e1, ull e2, ull e3,
        const float4& w, const float* __restrict__ vbt, int lane,
        float& o, float& wsum) {
#pragma unroll
    for (int j = 0; j < 4; ++j) {
        ull   mm = (j==0)?e0:(j==1)?e1:(j==2)?e2:e3;
        float ws = (j==0)?w.x:(j==1)?w.y:(j==2)?w.z:w.w;
        while (mm) {
            int l = (int)__ffsll(mm) - 1; mm &= mm - 1;
            float wa = readlane_f(ws, l);
            o = fmaf(wa, vbt[(size_t)(4*l + j)*VROW + lane], o);
            wsum += wa;
        }
    }
}

// Process the s-row and t-row for one (bh,p,t): joint bisection (scalar-pipe
// bracket updates), then batched gather: all 20 loads issued back-to-back,
// single drain, accumulate.
__device__ __forceinline__ void process_pair(
        const float4& a, const float4& b,
        const float* __restrict__ vbtS, const float* __restrict__ vbtT,
        int lane, float& osR, float& otR)
{
    BiState S, T;
    S.lo = T_LO; S.hi = T_HI; S.done = false; S.needEpi = true; S.tau = T_LO;
    T.lo = T_LO; T.hi = T_HI; T.done = false; T.needEpi = true; T.tau = T_LO;

    for (int it = 0; it < 40 && !(S.done && T.done); ++it) {
        bi_step(S, a, it);
        bi_step(T, b, it);
    }
    bi_finish(S, a);
    bi_finish(T, b);

    float4 wS = make_w(S, a);
    float4 wT = make_w(T, b);

    ull s0 = S.m0, s1 = S.m1, s2 = S.m2, s3 = S.m3;
    ull t0 = T.m0, t1 = T.m1, t2 = T.m2, t3 = T.m3;
    int   dS[NUMK], dT[NUMK];
    float fS[NUMK], fT[NUMK];
    extract10(s0, s1, s2, s3, wS, dS, fS);
    extract10(t0, t1, t2, t3, wT, dT, fT);

    // issue all 20 loads; compiler clusters them, one vmcnt drain at first use
    float gS[NUMK], gT[NUMK];
#pragma unroll
    for (int k = 0; k < NUMK; ++k) gS[k] = vbtS[(size_t)dS[k] * VROW + lane];
#pragma unroll
    for (int k = 0; k < NUMK; ++k) gT[k] = vbtT[(size_t)dT[k] * VROW + lane];

    float oS = 0.f, wsS = 0.f, oT = 0.f, wsT = 0.f;
#pragma unroll
    for (int k = 0; k < NUMK; ++k) { oS = fmaf(fS[k], gS[k], oS); wsS += fS[k]; }
#pragma unroll
    for (int k = 0; k < NUMK; ++k) { oT = fmaf(fT[k], gT[k], oT); wsT += fT[k]; }

    if (__builtin_expect((s0 | s1 | s2 | s3) != 0ull, 0))
        gather_tail(s0, s1, s2, s3, wS, vbtS, lane, oS, wsS);
    if (__builtin_expect((t0 | t1 | t2 | t3) != 0ull, 0))
        gather_tail(t0, t1, t2, t3, wT, vbtT, lane, oT, wsT);

    osR = oS * __builtin_amdgcn_rcpf(wsS);
    otR = oT * __builtin_amdgcn_rcpf(wsT);
}

__global__ __launch_bounds__(256, 4) void vtop_main(
        const float* __restrict__ att_s, const float* __restrict__ att_t,
        const float* __restrict__ v_s,   const float* __restrict__ v_t,
        float* __restrict__ partial) {
    int bid  = blockIdx.x;
    int p    = bid % PP;
    int bh   = bid / PP;
    int lane = threadIdx.x & 63;
    int wid  = threadIdx.x >> 6;

    size_t rowbase = ((size_t)bh * PP + p) * PP;
    const float* rs = att_s + rowbase;
    const float* rt = att_t + rowbase;
    size_t vbase = (size_t)bh * PP * HD;
    int t0 = wid * 2, t1 = t0 + 1;

    // hoist all 4 att-row loads: one HBM round trip for the whole wave
    float4 a0, b0, a1, b1;
    if (lane < 49) {            // 196 = 49*4; 16B-aligned (784 = 49*16)
        a0 = *(const float4*)(rs + t0 * DD + 4 * lane);
        b0 = *(const float4*)(rt + t0 * DD + 4 * lane);
        a1 = *(const float4*)(rs + t1 * DD + 4 * lane);
        b1 = *(const float4*)(rt + t1 * DD + 4 * lane);
    } else {
        float4 ninf; ninf.x = ninf.y = ninf.z = ninf.w = NEG_INF;
        a0 = b0 = a1 = b1 = ninf;
    }

    float acc = 0.f, os, ot;
    process_pair(a0, b0, v_s + vbase + t0 * HD, v_t + vbase + t0 * HD, lane, os, ot);
    { float d = os - ot; acc = fmaf(d, d, acc); }
    process_pair(a1, b1, v_s + vbase + t1 * HD, v_t + vbase + t1 * HD, lane, os, ot);
    { float d = os - ot; acc = fmaf(d, d, acc); }

    float wtot = wave_sum_u(acc);
    __shared__ float sm[4];
    if (lane == 0) sm[wid] = wtot;
    __syncthreads();
    if (threadIdx.x == 0) {
        partial[bid] = sm[0] + sm[1] + sm[2] + sm[3];
    }
}

// stage 1: 294 blocks x 256 -> 294 partials (parallel, latency-friendly)
__global__ __launch_bounds__(256) void vtop_reduce1(
        const float* __restrict__ partial, float* __restrict__ p2) {
    int i = blockIdx.x * 256 + threadIdx.x;
    float wtot = wave_sum_u(partial[i]);
    __shared__ float sm[4];
    int lane = threadIdx.x & 63, wid = threadIdx.x >> 6;
    if (lane == 0) sm[wid] = wtot;
    __syncthreads();
    if (threadIdx.x == 0) p2[blockIdx.x] = sm[0] + sm[1] + sm[2] + sm[3];
}

// stage 2: single block over 294 values
__global__ __launch_bounds__(256) void vtop_reduce2(
        const float* __restrict__ p2, float* __restrict__ out) {
    __shared__ double smd[256];
    double a = 0.0;
    for (int i = threadIdx.x; i < NRED1; i += 256) a += (double)p2[i];
    smd[threadIdx.x] = a;
    __syncthreads();
    for (int s = 128; s > 0; s >>= 1) {
        if (threadIdx.x < s) smd[threadIdx.x] += smd[threadIdx.x + s];
        __syncthreads();
    }
    if (threadIdx.x == 0) {
        const double inv_n = 1.0 / ((double)NBH * PP * TT * HD);  // 1/38535168
        out[0] = (float)(smd[0] * inv_n);
    }
}

extern "C" void kernel_launch(void* const* d_in, const int* in_sizes, int n_in,
                              void* d_out, int out_size, void* d_ws, size_t ws_size,
                              hipStream_t stream) {
    const float* att_s = (const float*)d_in[0];
    const float* att_t = (const float*)d_in[1];
    const float* v_s   = (const float*)d_in[2];
    const float* v_t   = (const float*)d_in[3];
    float* out     = (float*)d_out;
    float* partial = (float*)d_ws;                 // NBLK floats
    float* p2      = (float*)d_ws + NBLK;          // NRED1 floats

    vtop_main<<<NBLK, 256, 0, stream>>>(att_s, att_t, v_s, v_t, partial);
    vtop_reduce1<<<NRED1, 256, 0, stream>>>(partial, p2);
    vtop_reduce2<<<1, 256, 0, stream>>>(p2, out);
}

// Round 6
// 1566.316 us; speedup vs baseline: 1.0332x; 1.0081x over previous
//
#include <hip/hip_runtime.h>
#include <hip/hip_bf16.h>

// Problem constants (fixed by setup_inputs)
#define BB 4
#define HH 12
#define PP 1568
#define TT 8
#define DD 196          // PP / FRAME_T
#define HD 64
#define NUMK 10
#define NBH (BB*HH)     // 48
#define NBLK (NBH*PP)   // 75264
#define NRED1 (NBLK/256) // 294
#define VROW (TT*HD)    // 512 floats between consecutive d-rows of v
#define NEG_INF (-3.0e38f)

typedef unsigned long long ull;

__device__ __forceinline__ float readlane_f(float v, int l) {
    return __int_as_float(__builtin_amdgcn_readlane(__float_as_int(v), l));
}

// wave-wide sum, uniform result.
__device__ __forceinline__ float wave_sum_u(float v) {
#define STEPS(ctrl) { float t_ = __int_as_float(__builtin_amdgcn_update_dpp( \
        0, __float_as_int(v), ctrl, 0xF, 0xF, true)); v += t_; }
    STEPS(0x111) STEPS(0x112) STEPS(0x114) STEPS(0x118) STEPS(0x142) STEPS(0x143)
#undef STEPS
    return readlane_f(v, 63);
}

// Monotone u32 -> float order-preserving transform inverse.
__device__ __forceinline__ float untrans(unsigned v) {
    unsigned u = (v & 0x80000000u) ? (v ^ 0x80000000u) : ~v;
    return __uint_as_float(u);
}

#define T_LO 0x3E0FFFFFu   // t(-30.0f)
#define T_HI 0xC1F00000u   // t(+30.0f)
#define T_P0 0xC0400000u   // t(3.0f)  scripted probe 0
#define T_P1 0xBF800000u   // t(1.0f)  scripted probe 1

// Bisection state for one row (wave-uniform -> SGPRs).
struct BiState {
    unsigned lo, hi, tau;
    bool done, needEpi;
    ull m0, m1, m2, m3;
};

__device__ __forceinline__ void bi_init(BiState& st) {
    st.lo = T_LO; st.hi = T_HI; st.tau = T_LO;
    st.done = false; st.needEpi = true;
    st.m0 = st.m1 = st.m2 = st.m3 = 0ull;
}

__device__ __forceinline__ void bi_step(BiState& st, const float4& a, int it) {
    if (st.done) return;
    unsigned mid;
    if (it == 0)      mid = T_P0;
    else if (it == 1) mid = T_P1;
    else              mid = st.lo + ((st.hi - st.lo) >> 1);
    unsigned lo1 = st.lo + 1, hi1 = st.hi - 1;
    mid = (mid < lo1) ? lo1 : (mid > hi1) ? hi1 : mid;
    float tf = untrans(mid);
    ull c0 = __ballot(a.x >= tf);
    ull c1 = __ballot(a.y >= tf);
    ull c2 = __ballot(a.z >= tf);
    ull c3 = __ballot(a.w >= tf);
    int cnt = __popcll(c0) + __popcll(c1) + __popcll(c2) + __popcll(c3);
    cnt = __builtin_amdgcn_readfirstlane(cnt);
    if (cnt == NUMK) {
        st.tau = mid; st.done = true; st.needEpi = false;
        st.m0 = c0; st.m1 = c1; st.m2 = c2; st.m3 = c3;
    } else {
        if (cnt > NUMK) st.lo = mid; else st.hi = mid;
        if (st.hi - st.lo <= 1) {      // collapse: fp32 tie at the margin
            st.tau = st.lo; st.done = true; st.needEpi = true;
        }
    }
}

__device__ __forceinline__ void bi_finish(BiState& st, const float4& a) {
    if (st.needEpi) {   // recompute kept masks at final tau (rare path)
        float tf = untrans(st.tau);
        st.m0 = __ballot(a.x >= tf);
        st.m1 = __ballot(a.y >= tf);
        st.m2 = __ballot(a.z >= tf);
        st.m3 = __ballot(a.w >= tf);
    }
}

__device__ __forceinline__ float4 make_w(const BiState& st, const float4& a) {
    float tf = untrans(st.tau);
    float4 w;
    w.x = __expf(a.x - tf);
    w.y = __expf(a.y - tf);
    w.z = __expf(a.z - tf);
    w.w = __expf(a.w - tf);
    return w;
}

// Rare tail: kept elements beyond the first NUMK (exact fp32 ties). Inlined --
// a call boundary here forced accumulators to scratch in R4 (1.76 GB writes).
__device__ __forceinline__ void gather_tail(ull e0, ull e1, ull e2, ull e3,
        const float4& w, const float* __restrict__ vbt, int lane,
        float& o, float& wsum) {
#pragma unroll
    for (int j = 0; j < 4; ++j) {
        ull   mm = (j==0)?e0:(j==1)?e1:(j==2)?e2:e3;
        float ws = (j==0)?w.x:(j==1)?w.y:(j==2)?w.z:w.w;
        while (mm) {
            int l = (int)__ffsll(mm) - 1; mm &= mm - 1;
            float wa = readlane_f(ws, l);
            o = fmaf(wa, vbt[(size_t)(4*l + j)*VROW + lane], o);
            wsum += wa;
        }
    }
}

// ---- named-scalar extraction + load (NO arrays anywhere: hipcc's
// PromoteAlloca moved per-thread arrays to LDS in R5 -> 7.2e7 bank conflicts).
// Pops the lowest kept element from masks E0..E3, reads its weight (uniform,
// readlane -> SGPR), and ISSUES its v-row load. All SALU except ballot-derived
// selects; load lands in named VGPR G.
#define GRAB(E0,E1,E2,E3,W,VBT,G,F) \
    float G, F; { \
      ull  pick_ = E0 ? E0 : (E1 ? E1 : (E2 ? E2 : E3)); \
      int  j_    = E0 ? 0  : (E1 ? 1  : (E2 ? 2  : 3)); \
      int  l_    = (int)__ffsll(pick_) - 1; \
      ull  low_  = pick_ & (~pick_ + 1ull); \
      E0 = (j_==0) ? (E0^low_) : E0; \
      E1 = (j_==1) ? (E1^low_) : E1; \
      E2 = (j_==2) ? (E2^low_) : E2; \
      E3 = (j_==3) ? (E3^low_) : E3; \
      float wsel_ = (j_==0)?W.x:(j_==1)?W.y:(j_==2)?W.z:W.w; \
      F = readlane_f(wsel_, l_); \
      G = VBT[(size_t)(4*l_+j_)*VROW + lane]; }

#define GRAB10(E0,E1,E2,E3,W,VBT,G,F) \
    GRAB(E0,E1,E2,E3,W,VBT,G##0,F##0) \
    GRAB(E0,E1,E2,E3,W,VBT,G##1,F##1) \
    GRAB(E0,E1,E2,E3,W,VBT,G##2,F##2) \
    GRAB(E0,E1,E2,E3,W,VBT,G##3,F##3) \
    GRAB(E0,E1,E2,E3,W,VBT,G##4,F##4) \
    GRAB(E0,E1,E2,E3,W,VBT,G##5,F##5) \
    GRAB(E0,E1,E2,E3,W,VBT,G##6,F##6) \
    GRAB(E0,E1,E2,E3,W,VBT,G##7,F##7) \
    GRAB(E0,E1,E2,E3,W,VBT,G##8,F##8) \
    GRAB(E0,E1,E2,E3,W,VBT,G##9,F##9)

#define ACC10(G,F,O,WS) \
    float O = 0.f, WS = 0.f; \
    O = fmaf(F##0,G##0,O); WS += F##0; \
    O = fmaf(F##1,G##1,O); WS += F##1; \
    O = fmaf(F##2,G##2,O); WS += F##2; \
    O = fmaf(F##3,G##3,O); WS += F##3; \
    O = fmaf(F##4,G##4,O); WS += F##4; \
    O = fmaf(F##5,G##5,O); WS += F##5; \
    O = fmaf(F##6,G##6,O); WS += F##6; \
    O = fmaf(F##7,G##7,O); WS += F##7; \
    O = fmaf(F##8,G##8,O); WS += F##8; \
    O = fmaf(F##9,G##9,O); WS += F##9;

__global__ __launch_bounds__(256, 4) void vtop_main(
        const float* __restrict__ att_s, const float* __restrict__ att_t,
        const float* __restrict__ v_s,   const float* __restrict__ v_t,
        float* __restrict__ partial) {
    int bid  = blockIdx.x;
    int p    = bid % PP;
    int bh   = bid / PP;
    int lane = threadIdx.x & 63;
    int wid  = threadIdx.x >> 6;

    size_t rowbase = ((size_t)bh * PP + p) * PP;
    const float* rs = att_s + rowbase;
    const float* rt = att_t + rowbase;
    size_t vbase = (size_t)bh * PP * HD;
    int t0 = wid * 2, t1 = t0 + 1;

    // hoist all 4 att-row loads: one HBM round trip for the whole wave
    float4 a0, b0, a1, b1;
    if (lane < 49) {            // 196 = 49*4; rows are 16B-aligned (784*4B)
        a0 = *(const float4*)(rs + t0 * DD + 4 * lane);
        b0 = *(const float4*)(rt + t0 * DD + 4 * lane);
        a1 = *(const float4*)(rs + t1 * DD + 4 * lane);
        b1 = *(const float4*)(rt + t1 * DD + 4 * lane);
    } else {
        float4 ninf; ninf.x = ninf.y = ninf.z = ninf.w = NEG_INF;
        a0 = b0 = a1 = b1 = ninf;
    }

    // joint bisection of all 4 rows (wave-uniform; bracket updates on SALU)
    BiState S0, T0, S1, T1;
    bi_init(S0); bi_init(T0); bi_init(S1); bi_init(T1);
    for (int it = 0;
         it < 40 && !(S0.done && T0.done && S1.done && T1.done); ++it) {
        bi_step(S0, a0, it);
        bi_step(T0, b0, it);
        bi_step(S1, a1, it);
        bi_step(T1, b1, it);
    }
    bi_finish(S0, a0); bi_finish(T0, b0);
    bi_finish(S1, a1); bi_finish(T1, b1);

    float4 wS0 = make_w(S0, a0), wT0 = make_w(T0, b0);
    float4 wS1 = make_w(S1, a1), wT1 = make_w(T1, b1);

    const float* vS0 = v_s + vbase + t0 * HD;
    const float* vT0 = v_t + vbase + t0 * HD;
    const float* vS1 = v_s + vbase + t1 * HD;
    const float* vT1 = v_t + vbase + t1 * HD;

    ull s00 = S0.m0, s01 = S0.m1, s02 = S0.m2, s03 = S0.m3;
    ull u00 = T0.m0, u01 = T0.m1, u02 = T0.m2, u03 = T0.m3;
    ull s10 = S1.m0, s11 = S1.m1, s12 = S1.m2, s13 = S1.m3;
    ull u10 = T1.m0, u11 = T1.m1, u12 = T1.m2, u13 = T1.m3;

    // all 40 gather loads issued back-to-back: ONE round trip for the wave
    GRAB10(s00, s01, s02, s03, wS0, vS0, gA, fA)
    GRAB10(u00, u01, u02, u03, wT0, vT0, gB, fB)
    GRAB10(s10, s11, s12, s13, wS1, vS1, gC, fC)
    GRAB10(u10, u11, u12, u13, wT1, vT1, gD, fD)

    ACC10(gA, fA, oS0, wsS0)
    ACC10(gB, fB, oT0, wsT0)
    ACC10(gC, fC, oS1, wsS1)
    ACC10(gD, fD, oT1, wsT1)

    // rare fp32-tie tails (kept count > 10)
    if (__builtin_expect((s00|s01|s02|s03) != 0ull, 0))
        gather_tail(s00, s01, s02, s03, wS0, vS0, lane, oS0, wsS0);
    if (__builtin_expect((u00|u01|u02|u03) != 0ull, 0))
        gather_tail(u00, u01, u02, u03, wT0, vT0, lane, oT0, wsT0);
    if (__builtin_expect((s10|s11|s12|s13) != 0ull, 0))
        gather_tail(s10, s11, s12, s13, wS1, vS1, lane, oS1, wsS1);
    if (__builtin_expect((u10|u11|u12|u13) != 0ull, 0))
        gather_tail(u10, u11, u12, u13, wT1, vT1, lane, oT1, wsT1);

    float d0 = oS0 * __builtin_amdgcn_rcpf(wsS0) - oT0 * __builtin_amdgcn_rcpf(wsT0);
    float d1 = oS1 * __builtin_amdgcn_rcpf(wsS1) - oT1 * __builtin_amdgcn_rcpf(wsT1);
    float acc = fmaf(d0, d0, d1 * d1);

    float wtot = wave_sum_u(acc);
    __shared__ float sm[4];
    if (lane == 0) sm[wid] = wtot;
    __syncthreads();
    if (threadIdx.x == 0) {
        partial[bid] = sm[0] + sm[1] + sm[2] + sm[3];
    }
}

// stage 1: 294 blocks x 256 -> 294 partials
__global__ __launch_bounds__(256) void vtop_reduce1(
        const float* __restrict__ partial, float* __restrict__ p2) {
    int i = blockIdx.x * 256 + threadIdx.x;
    float wtot = wave_sum_u(partial[i]);
    __shared__ float sm[4];
    int lane = threadIdx.x & 63, wid = threadIdx.x >> 6;
    if (lane == 0) sm[wid] = wtot;
    __syncthreads();
    if (threadIdx.x == 0) p2[blockIdx.x] = sm[0] + sm[1] + sm[2] + sm[3];
}

// stage 2: single block over 294 values
__global__ __launch_bounds__(256) void vtop_reduce2(
        const float* __restrict__ p2, float* __restrict__ out) {
    __shared__ double smd[256];
    double a = 0.0;
    for (int i = threadIdx.x; i < NRED1; i += 256) a += (double)p2[i];
    smd[threadIdx.x] = a;
    __syncthreads();
    for (int s = 128; s > 0; s >>= 1) {
        if (threadIdx.x < s) smd[threadIdx.x] += smd[threadIdx.x + s];
        __syncthreads();
    }
    if (threadIdx.x == 0) {
        const double inv_n = 1.0 / ((double)NBH * PP * TT * HD);  // 1/38535168
        out[0] = (float)(smd[0] * inv_n);
    }
}

extern "C" void kernel_launch(void* const* d_in, const int* in_sizes, int n_in,
                              void* d_out, int out_size, void* d_ws, size_t ws_size,
                              hipStream_t stream) {
    const float* att_s = (const float*)d_in[0];
    const float* att_t = (const float*)d_in[1];
    const float* v_s   = (const float*)d_in[2];
    const float* v_t   = (const float*)d_in[3];
    float* out     = (float*)d_out;
    float* partial = (float*)d_ws;                 // NBLK floats
    float* p2      = (float*)d_ws + NBLK;          // NRED1 floats

    vtop_main<<<NBLK, 256, 0, stream>>>(att_s, att_t, v_s, v_t, partial);
    vtop_reduce1<<<NRED1, 256, 0, stream>>>(partial, p2);
    vtop_reduce2<<<1, 256, 0, stream>>>(p2, out);
}